// Round 4
// baseline (179.509 us; speedup 1.0000x reference)
//
#include <hip/hip_runtime.h>

#define SEQ 4096
#define EMB 768
#define NH 12
#define HD 64
#define KDIM 768
#define LNEG -100000000.0f
#define LOG2E 1.44269504f

typedef __attribute__((ext_vector_type(8))) short short8;
typedef __attribute__((ext_vector_type(4))) short short4v;
typedef __attribute__((ext_vector_type(4))) float f32x4;

__device__ inline unsigned short f2bf(float f) {
    unsigned int u = __float_as_uint(f);
    u += 0x7fffu + ((u >> 16) & 1u);
    return (unsigned short)(u >> 16);
}
__device__ inline float bf2f(unsigned short s) {
    unsigned int u = ((unsigned int)s) << 16;
    return __uint_as_float(u);
}

__device__ inline short8 cat8(short4v lo, short4v hi) {
    return __builtin_shufflevector(lo, hi, 0, 1, 2, 3, 4, 5, 6, 7);
}

__device__ inline void gload_lds16(const unsigned short* g, unsigned short* l) {
    __builtin_amdgcn_global_load_lds(
        (const __attribute__((address_space(1))) void*)g,
        (__attribute__((address_space(3))) void*)l, 16, 0, 0);
}

// ---------------- Prep: hid -> bf16, W -> W^T bf16 (q-scale*log2e folded into Wq) ----------------
__global__ __launch_bounds__(256) void prep_kernel(
    const float* __restrict__ hid,
    const float* __restrict__ Wq, const float* __restrict__ Wk, const float* __restrict__ Wv,
    unsigned short* __restrict__ hidb,   // [4096][768] bf16
    unsigned short* __restrict__ Wt)     // [2304][768] bf16, [n][k]
{
    const int bid = blockIdx.x;
    const int t = threadIdx.x;
    if (bid >= 432) {
        int vid = (bid - 432) * 256 + t;
        const int nch = SEQ * EMB / 4;
        const int stride = 576 * 256;
        for (int c = vid; c < nch; c += stride) {
            f32x4 v = ((const f32x4*)hid)[c];
            short4v o;
            #pragma unroll
            for (int x = 0; x < 4; x++) o[x] = (short)f2bf(v[x]);
            ((short4v*)hidb)[c] = o;
        }
        return;
    }
    const int mat = bid / 144;
    const int r2 = bid % 144;
    const int k0 = (r2 % 12) * 64;
    const int n0 = (r2 / 12) * 64;
    const float* Wm = (mat == 0) ? Wq : (mat == 1 ? Wk : Wv);
    const float scale = (mat == 0) ? 0.125f * LOG2E : 1.0f;
    __shared__ unsigned short Lt[64 * 82];
    #pragma unroll
    for (int i = 0; i < 4; i++) {
        int row = i * 16 + (t >> 4);
        int col = (t & 15) * 4;
        f32x4 v = *(const f32x4*)(Wm + (size_t)(k0 + row) * EMB + n0 + col);
        #pragma unroll
        for (int x = 0; x < 4; x++)
            Lt[(col + x) * 82 + row] = f2bf(v[x] * scale);
    }
    __syncthreads();
    #pragma unroll
    for (int j = 0; j < 2; j++) {
        int idx = j * 256 + t;
        int nr = idx >> 3;
        int kc = (idx & 7) * 8;
        short8 o = *(const short8*)(Lt + nr * 82 + kc);
        *(short8*)(Wt + (size_t)(mat * 768 + n0 + nr) * KDIM + k0 + kc) = o;
    }
}

// ---------------- GEMM: 64x128 tiles, grid (64,18); LDS-bounce coalesced epilogue ----------------
__global__ __launch_bounds__(256) void gemm_kernel(
    const unsigned short* __restrict__ hidb,
    const unsigned short* __restrict__ Wt,
    const float* __restrict__ bq, const float* __restrict__ bk, const float* __restrict__ bv,
    unsigned short* __restrict__ q_ws,   // [H][S][D] bf16
    unsigned short* __restrict__ k_ws,   // [H][S][D] bf16
    unsigned short* __restrict__ v_ws)   // [H][D][S] bf16
{
    const int m0 = blockIdx.x * 64;
    const int n0 = blockIdx.y * 128;
    __shared__ union {
        struct { unsigned short Al[64 * 64]; unsigned short Bl[128 * 64]; } s;  // 24 KB
        unsigned short Cqk[64 * 136];   // 17.4 KB, stride 136 (272B, 16B-aligned rows)
        unsigned short Cv[128 * 72];    // 18.4 KB, stride 72 (144B, 16B-aligned rows)
    } sm;
    const int t = threadIdx.x;
    const int wave = t >> 6, lane = t & 63;
    const int quad = lane >> 4, l16 = lane & 15;

    const f32x4 zero = {0.f, 0.f, 0.f, 0.f};
    f32x4 acc[4][2];
    #pragma unroll
    for (int i = 0; i < 4; i++)
        #pragma unroll
        for (int j = 0; j < 2; j++) acc[i][j] = zero;

    for (int k0 = 0; k0 < KDIM; k0 += 64) {
        #pragma unroll
        for (int i = 0; i < 2; i++) {
            int c = (wave * 2 + i) * 64 + lane;
            int row = c >> 3;
            int kc = ((c & 7) ^ (row & 7)) * 8;
            gload_lds16(hidb + (size_t)(m0 + row) * KDIM + k0 + kc, sm.s.Al + (wave * 2 + i) * 512);
        }
        #pragma unroll
        for (int i = 0; i < 4; i++) {
            int c = (wave * 4 + i) * 64 + lane;
            int row = c >> 3;
            int kc = ((c & 7) ^ (row & 7)) * 8;
            gload_lds16(Wt + (size_t)(n0 + row) * KDIM + k0 + kc, sm.s.Bl + (wave * 4 + i) * 512);
        }
        __syncthreads();

        short8 af[2][4], bfr[2][2];
        #pragma unroll
        for (int rt = 0; rt < 4; rt++) {
            int rowA = rt * 16 + l16;
            #pragma unroll
            for (int s = 0; s < 2; s++)
                af[s][rt] = *(const short8*)(sm.s.Al + rowA * 64 + (((s << 2) | quad) ^ (rowA & 7)) * 8);
        }
        #pragma unroll
        for (int ct = 0; ct < 2; ct++) {
            int rowB = wave * 32 + ct * 16 + l16;
            #pragma unroll
            for (int s = 0; s < 2; s++)
                bfr[s][ct] = *(const short8*)(sm.s.Bl + rowB * 64 + (((s << 2) | quad) ^ (rowB & 7)) * 8);
        }
        #pragma unroll
        for (int s = 0; s < 2; s++)
            #pragma unroll
            for (int rt = 0; rt < 4; rt++)
                #pragma unroll
                for (int ct = 0; ct < 2; ct++)
                    acc[rt][ct] = __builtin_amdgcn_mfma_f32_16x16x32_bf16(af[s][rt], bfr[s][ct], acc[rt][ct], 0, 0, 0);
        __syncthreads();
    }

    const int mat = blockIdx.y / 6;
    const float* bm = (mat == 0) ? bq : (mat == 1 ? bk : bv);
    const float bscale = (mat == 0) ? 0.125f * LOG2E : 1.0f;

    if (mat != 2) {
        #pragma unroll
        for (int ct = 0; ct < 2; ct++) {
            int nloc = wave * 32 + ct * 16 + l16;
            float bias = bm[(n0 + nloc) - mat * 768] * bscale;
            #pragma unroll
            for (int rt = 0; rt < 4; rt++)
                #pragma unroll
                for (int r = 0; r < 4; r++)
                    sm.Cqk[(rt * 16 + quad * 4 + r) * 136 + nloc] = f2bf(acc[rt][ct][r] + bias);
        }
        __syncthreads();
        unsigned short* dst_ws = (mat == 0) ? q_ws : k_ws;
        #pragma unroll
        for (int p = 0; p < 4; p++) {
            int id = p * 256 + t;            // 1024 = 64 rows x 16 chunks
            int row = id >> 4, nc = id & 15;
            short8 val = *(const short8*)(sm.Cqk + row * 136 + nc * 8);
            int within = (n0 + nc * 8) - mat * 768;
            int head = within >> 6, dd = within & 63;
            *(short8*)(dst_ws + (size_t)head * (SEQ * HD) + (size_t)(m0 + row) * HD + dd) = val;
        }
    } else {
        #pragma unroll
        for (int ct = 0; ct < 2; ct++) {
            int nloc = wave * 32 + ct * 16 + l16;
            float bias = bm[(n0 + nloc) - 1536];
            #pragma unroll
            for (int rt = 0; rt < 4; rt++)
                #pragma unroll
                for (int r = 0; r < 4; r++)
                    sm.Cv[nloc * 72 + rt * 16 + quad * 4 + r] = f2bf(acc[rt][ct][r] + bias);
        }
        __syncthreads();
        #pragma unroll
        for (int p = 0; p < 4; p++) {
            int id = p * 256 + t;            // 1024 = 128 dd x 8 chunks
            int ddl = id >> 3;
            int sseg = (id & 7) * 8;
            short8 val = *(const short8*)(sm.Cv + ddl * 72 + sseg);
            int within = (n0 + ddl) - 1536;
            int head = within >> 6, dd = within & 63;
            *(short8*)(v_ws + (size_t)head * (HD * SEQ) + (size_t)dd * SEQ + m0 + sseg) = val;
        }
    }
}

// ---------------- Banded attention R4: streaming swapped-operand, f2bf pack ----------------
// R3 failed at absmax 2.6e-2 ~ output magnitude => structural error on adjacent
// elements. All fragment algebra is verified by the original kernel's passing
// config (identity (quad,elem) pairing); the one unverified piece was the
// v_cvt_pk_bf16_f32 asm (pack order / rounding). R4 replaces it with the
// bit-exact pack of the previously-passing kernels: pb = f2bf(e) (manual RNE),
// packed pairwise; row-sum accumulates the ROUNDED bf2f(pb) values, matching
// old numerics exactly. Structure unchanged from R3: S^T = mfma(K, Q) so each
// lane owns P[qrow=l16][keys]; P -> PV B-operand in registers; V^T A-operand
// with matching per-quad key order (two 8B loads); no P LDS; one barrier;
// LDS 2.4 KB; 768 WGs x 4 waves = 3 WGs/CU fully resident.
__global__ __launch_bounds__(256, 3) void attn_kernel(
    const unsigned short* __restrict__ q_ws,
    const unsigned short* __restrict__ k_ws,
    const unsigned short* __restrict__ v_ws,
    const float* __restrict__ amask,
    const unsigned char* __restrict__ imask,
    float* __restrict__ out)
{
    const int lbid = blockIdx.x;                  // 768 = 8 XCD * 96
    const int xcd = lbid & 7, slot = lbid >> 3;
    const int wg = xcd * 96 + slot;               // bijective (768 % 8 == 0)
    const int h = wg >> 6, c = wg & 63;
    const int i0 = c * 64;
    const int t = threadIdx.x;
    const int wave = t >> 6, lane = t & 63;
    const int quad = lane >> 4, l16 = lane & 15;
    const bool interior = (c >= 4) && (c <= 58);  // whole WG span [i0-256, i0+336) in-bounds

    __shared__ float fm[592];                     // per-key mask (log2 domain), WG span

    const int base = i0 - 256;
    for (int cc = t; cc < 592; cc += 256) {
        int j = base + cc;
        float f;
        if (interior)
            f = (amask[j] != 0.0f) ? LNEG * LOG2E : 0.0f;
        else
            f = ((unsigned)j >= SEQ) ? -1e30f : ((amask[j] != 0.0f) ? LNEG * LOG2E : 0.0f);
        fm[cc] = f;
    }
    __syncthreads();   // only barrier in the kernel

    const int row_g = i0 + wave * 16 + l16;       // this lane's q-row
    const int j0w = i0 + wave * 16 - 256;         // wave key-window origin
    const int fmoff = wave * 16;                  // fm index offset for this wave

    // Q (B-operand): col=l16=qrow, k=dd
    const unsigned short* qb = q_ws + h * (SEQ * HD) + (size_t)row_g * HD + quad * 8;
    short8 a0 = *(const short8*)qb;
    short8 a1 = *(const short8*)(qb + 32);

    const unsigned short* kh = k_ws + h * (SEQ * HD);
    const unsigned short* vh = v_ws + h * (HD * SEQ) + (size_t)l16 * SEQ;  // A-row = l16 = dd_local

    const f32x4 zero = {0.f, 0.f, 0.f, 0.f};
    f32x4 acc0 = zero, acc1 = zero, acc2 = zero, acc3 = zero;
    float sum = 0.f;

    if (interior) {
        #pragma unroll 2
        for (int g = 0; g < 17; ++g) {
            const int kb = j0w + 32 * g;
            // K tiles (A-operand): row=l16=key, k=dd
            const unsigned short* kp0 = kh + (size_t)(kb + l16) * HD + quad * 8;
            const unsigned short* kp1 = kh + (size_t)(kb + 16 + l16) * HD + quad * 8;
            short8 k00 = *(const short8*)kp0;
            short8 k01 = *(const short8*)(kp0 + 32);
            short8 k10 = *(const short8*)kp1;
            short8 k11 = *(const short8*)(kp1 + 32);
            // V^T (A-operand) with per-quad key order: j0..3 = t0 keys 4q.., j4..7 = t1 keys 4q..
            const unsigned short* vp = vh + kb + 4 * quad;
            short4v v00 = *(const short4v*)(vp);
            short4v v01 = *(const short4v*)(vp + 16);
            short4v v10 = *(const short4v*)(vp + 16 * SEQ);
            short4v v11 = *(const short4v*)(vp + 16 * SEQ + 16);
            short4v v20 = *(const short4v*)(vp + 32 * SEQ);
            short4v v21 = *(const short4v*)(vp + 32 * SEQ + 16);
            short4v v30 = *(const short4v*)(vp + 48 * SEQ);
            short4v v31 = *(const short4v*)(vp + 48 * SEQ + 16);
            // fm for this lane's 8 keys
            f32x4 fm0 = *(const f32x4*)(fm + fmoff + 32 * g + 4 * quad);
            f32x4 fm1 = *(const f32x4*)(fm + fmoff + 32 * g + 16 + 4 * quad);
            // S^T tiles: D row = key_local (quad*4+r), col = l16 = qrow
            f32x4 s0 = zero, s1 = zero;
            s0 = __builtin_amdgcn_mfma_f32_16x16x32_bf16(k00, a0, s0, 0, 0, 0);
            s0 = __builtin_amdgcn_mfma_f32_16x16x32_bf16(k01, a1, s0, 0, 0, 0);
            s1 = __builtin_amdgcn_mfma_f32_16x16x32_bf16(k10, a0, s1, 0, 0, 0);
            s1 = __builtin_amdgcn_mfma_f32_16x16x32_bf16(k11, a1, s1, 0, 0, 0);
            // mask + exp2 + RNE-bf16 round + row-sum (band: 0 <= cc - l16 <= 512)
            unsigned short pb[8];
            #pragma unroll
            for (int r = 0; r < 4; ++r) {
                int cc0 = 32 * g + 4 * quad + r;
                float arg0 = ((unsigned)(cc0 - l16) <= 512u) ? (s0[r] + fm0[r]) : -1e30f;
                unsigned short p0 = f2bf(__builtin_amdgcn_exp2f(arg0));
                pb[r] = p0; sum += bf2f(p0);
                int cc1 = cc0 + 16;
                float arg1 = ((unsigned)(cc1 - l16) <= 512u) ? (s1[r] + fm1[r]) : -1e30f;
                unsigned short p1 = f2bf(__builtin_amdgcn_exp2f(arg1));
                pb[4 + r] = p1; sum += bf2f(p1);
            }
            union { unsigned int u[4]; short8 s8; } pf;
            pf.u[0] = (unsigned int)pb[0] | ((unsigned int)pb[1] << 16);
            pf.u[1] = (unsigned int)pb[2] | ((unsigned int)pb[3] << 16);
            pf.u[2] = (unsigned int)pb[4] | ((unsigned int)pb[5] << 16);
            pf.u[3] = (unsigned int)pb[6] | ((unsigned int)pb[7] << 16);
            // PV: O^T tiles, D row = dd_local, col = l16 = qrow
            acc0 = __builtin_amdgcn_mfma_f32_16x16x32_bf16(cat8(v00, v01), pf.s8, acc0, 0, 0, 0);
            acc1 = __builtin_amdgcn_mfma_f32_16x16x32_bf16(cat8(v10, v11), pf.s8, acc1, 0, 0, 0);
            acc2 = __builtin_amdgcn_mfma_f32_16x16x32_bf16(cat8(v20, v21), pf.s8, acc2, 0, 0, 0);
            acc3 = __builtin_amdgcn_mfma_f32_16x16x32_bf16(cat8(v30, v31), pf.s8, acc3, 0, 0, 0);
        }
    } else {
        #pragma unroll 2
        for (int g = 0; g < 17; ++g) {
            const int kb = j0w + 32 * g;
            int jk0 = min(max(kb + l16, 0), SEQ - 1);
            int jk1 = min(max(kb + 16 + l16, 0), SEQ - 1);
            const unsigned short* kp0 = kh + (size_t)jk0 * HD + quad * 8;
            const unsigned short* kp1 = kh + (size_t)jk1 * HD + quad * 8;
            short8 k00 = *(const short8*)kp0;
            short8 k01 = *(const short8*)(kp0 + 32);
            short8 k10 = *(const short8*)kp1;
            short8 k11 = *(const short8*)(kp1 + 32);
            int kv0 = min(max(kb + 4 * quad, 0), SEQ - 4);
            int kv1 = min(max(kb + 16 + 4 * quad, 0), SEQ - 4);
            short4v v00 = *(const short4v*)(vh + kv0);
            short4v v01 = *(const short4v*)(vh + kv1);
            short4v v10 = *(const short4v*)(vh + 16 * SEQ + kv0);
            short4v v11 = *(const short4v*)(vh + 16 * SEQ + kv1);
            short4v v20 = *(const short4v*)(vh + 32 * SEQ + kv0);
            short4v v21 = *(const short4v*)(vh + 32 * SEQ + kv1);
            short4v v30 = *(const short4v*)(vh + 48 * SEQ + kv0);
            short4v v31 = *(const short4v*)(vh + 48 * SEQ + kv1);
            f32x4 fm0 = *(const f32x4*)(fm + fmoff + 32 * g + 4 * quad);
            f32x4 fm1 = *(const f32x4*)(fm + fmoff + 32 * g + 16 + 4 * quad);
            f32x4 s0 = zero, s1 = zero;
            s0 = __builtin_amdgcn_mfma_f32_16x16x32_bf16(k00, a0, s0, 0, 0, 0);
            s0 = __builtin_amdgcn_mfma_f32_16x16x32_bf16(k01, a1, s0, 0, 0, 0);
            s1 = __builtin_amdgcn_mfma_f32_16x16x32_bf16(k10, a0, s1, 0, 0, 0);
            s1 = __builtin_amdgcn_mfma_f32_16x16x32_bf16(k11, a1, s1, 0, 0, 0);
            unsigned short pb[8];
            #pragma unroll
            for (int r = 0; r < 4; ++r) {
                int cc0 = 32 * g + 4 * quad + r;
                float arg0 = ((unsigned)(cc0 - l16) <= 512u) ? (s0[r] + fm0[r]) : -1e30f;
                unsigned short p0 = f2bf(__builtin_amdgcn_exp2f(arg0));
                pb[r] = p0; sum += bf2f(p0);
                int cc1 = cc0 + 16;
                float arg1 = ((unsigned)(cc1 - l16) <= 512u) ? (s1[r] + fm1[r]) : -1e30f;
                unsigned short p1 = f2bf(__builtin_amdgcn_exp2f(arg1));
                pb[4 + r] = p1; sum += bf2f(p1);
            }
            union { unsigned int u[4]; short8 s8; } pf;
            pf.u[0] = (unsigned int)pb[0] | ((unsigned int)pb[1] << 16);
            pf.u[1] = (unsigned int)pb[2] | ((unsigned int)pb[3] << 16);
            pf.u[2] = (unsigned int)pb[4] | ((unsigned int)pb[5] << 16);
            pf.u[3] = (unsigned int)pb[6] | ((unsigned int)pb[7] << 16);
            acc0 = __builtin_amdgcn_mfma_f32_16x16x32_bf16(cat8(v00, v01), pf.s8, acc0, 0, 0, 0);
            acc1 = __builtin_amdgcn_mfma_f32_16x16x32_bf16(cat8(v10, v11), pf.s8, acc1, 0, 0, 0);
            acc2 = __builtin_amdgcn_mfma_f32_16x16x32_bf16(cat8(v20, v21), pf.s8, acc2, 0, 0, 0);
            acc3 = __builtin_amdgcn_mfma_f32_16x16x32_bf16(cat8(v30, v31), pf.s8, acc3, 0, 0, 0);
        }
    }

    // row-sum across quads (lanes sharing l16) and normalize + write O^T
    sum += __shfl_xor(sum, 16);
    sum += __shfl_xor(sum, 32);
    float rinv = imask[row_g] ? 0.f : __builtin_amdgcn_rcpf(sum);

    float* ob = out + (size_t)row_g * EMB + h * HD + quad * 4;
    f32x4 o;
    #pragma unroll
    for (int r = 0; r < 4; ++r) o[r] = acc0[r] * rinv;
    *(f32x4*)(ob) = o;
    #pragma unroll
    for (int r = 0; r < 4; ++r) o[r] = acc1[r] * rinv;
    *(f32x4*)(ob + 16) = o;
    #pragma unroll
    for (int r = 0; r < 4; ++r) o[r] = acc2[r] * rinv;
    *(f32x4*)(ob + 32) = o;
    #pragma unroll
    for (int r = 0; r < 4; ++r) o[r] = acc3[r] * rinv;
    *(f32x4*)(ob + 48) = o;
}

extern "C" void kernel_launch(void* const* d_in, const int* in_sizes, int n_in,
                              void* d_out, int out_size, void* d_ws, size_t ws_size,
                              hipStream_t stream) {
    (void)in_sizes; (void)n_in; (void)out_size; (void)ws_size;
    const float* hid = (const float*)d_in[0];
    const float* am  = (const float*)d_in[1];
    const unsigned char* im = (const unsigned char*)d_in[2];
    const float* Wq = (const float*)d_in[3];
    const float* bq = (const float*)d_in[4];
    const float* Wk = (const float*)d_in[5];
    const float* bk = (const float*)d_in[6];
    const float* Wv = (const float*)d_in[7];
    const float* bv = (const float*)d_in[8];
    float* out = (float*)d_out;

    unsigned short* ws = (unsigned short*)d_ws;
    unsigned short* q_ws = ws;
    unsigned short* k_ws = ws + (size_t)NH * SEQ * HD;
    unsigned short* v_ws = ws + 2 * (size_t)NH * SEQ * HD;
    unsigned short* hidb = (unsigned short*)d_out;   // d_out as scratch (attn overwrites last)
    unsigned short* Wt   = hidb + (size_t)SEQ * EMB;

    prep_kernel<<<dim3(1008), 256, 0, stream>>>(hid, Wq, Wk, Wv, hidb, Wt);
    gemm_kernel<<<dim3(64, 18), 256, 0, stream>>>(hidb, Wt, bq, bk, bv, q_ws, k_ws, v_ws);
    attn_kernel<<<dim3(768), 256, 0, stream>>>(q_ws, k_ws, v_ws, am, im, out);
}

// Round 5
// 133.846 us; speedup vs baseline: 1.3412x; 1.3412x over previous
//
#include <hip/hip_runtime.h>

#define SEQ 4096
#define EMB 768
#define NH 12
#define HD 64
#define KDIM 768
#define LNEG -100000000.0f
#define LOG2E 1.44269504f

typedef __attribute__((ext_vector_type(8))) short short8;
typedef __attribute__((ext_vector_type(4))) short short4v;
typedef __attribute__((ext_vector_type(4))) float f32x4;

__device__ inline unsigned short f2bf(float f) {
    unsigned int u = __float_as_uint(f);
    u += 0x7fffu + ((u >> 16) & 1u);
    return (unsigned short)(u >> 16);
}
__device__ inline float bf2f(unsigned short s) {
    unsigned int u = ((unsigned int)s) << 16;
    return __uint_as_float(u);
}

__device__ inline short8 cat8(short4v lo, short4v hi) {
    return __builtin_shufflevector(lo, hi, 0, 1, 2, 3, 4, 5, 6, 7);
}

__device__ inline void gload_lds16(const unsigned short* g, unsigned short* l) {
    __builtin_amdgcn_global_load_lds(
        (const __attribute__((address_space(1))) void*)g,
        (__attribute__((address_space(3))) void*)l, 16, 0, 0);
}

// ---------------- Prep: hid -> bf16, W -> W^T bf16 (q-scale*log2e folded into Wq) ----------------
__global__ __launch_bounds__(256) void prep_kernel(
    const float* __restrict__ hid,
    const float* __restrict__ Wq, const float* __restrict__ Wk, const float* __restrict__ Wv,
    unsigned short* __restrict__ hidb,   // [4096][768] bf16
    unsigned short* __restrict__ Wt)     // [2304][768] bf16, [n][k]
{
    const int bid = blockIdx.x;
    const int t = threadIdx.x;
    if (bid >= 432) {
        int vid = (bid - 432) * 256 + t;
        const int nch = SEQ * EMB / 4;
        const int stride = 576 * 256;
        for (int c = vid; c < nch; c += stride) {
            f32x4 v = ((const f32x4*)hid)[c];
            short4v o;
            #pragma unroll
            for (int x = 0; x < 4; x++) o[x] = (short)f2bf(v[x]);
            ((short4v*)hidb)[c] = o;
        }
        return;
    }
    const int mat = bid / 144;
    const int r2 = bid % 144;
    const int k0 = (r2 % 12) * 64;
    const int n0 = (r2 / 12) * 64;
    const float* Wm = (mat == 0) ? Wq : (mat == 1 ? Wk : Wv);
    const float scale = (mat == 0) ? 0.125f * LOG2E : 1.0f;
    __shared__ unsigned short Lt[64 * 82];
    #pragma unroll
    for (int i = 0; i < 4; i++) {
        int row = i * 16 + (t >> 4);
        int col = (t & 15) * 4;
        f32x4 v = *(const f32x4*)(Wm + (size_t)(k0 + row) * EMB + n0 + col);
        #pragma unroll
        for (int x = 0; x < 4; x++)
            Lt[(col + x) * 82 + row] = f2bf(v[x] * scale);
    }
    __syncthreads();
    #pragma unroll
    for (int j = 0; j < 2; j++) {
        int idx = j * 256 + t;
        int nr = idx >> 3;
        int kc = (idx & 7) * 8;
        short8 o = *(const short8*)(Lt + nr * 82 + kc);
        *(short8*)(Wt + (size_t)(mat * 768 + n0 + nr) * KDIM + k0 + kc) = o;
    }
}

// ---------------- GEMM: 64x128 tiles, grid (64,18); LDS-bounce coalesced epilogue ----------------
__global__ __launch_bounds__(256) void gemm_kernel(
    const unsigned short* __restrict__ hidb,
    const unsigned short* __restrict__ Wt,
    const float* __restrict__ bq, const float* __restrict__ bk, const float* __restrict__ bv,
    unsigned short* __restrict__ q_ws,   // [H][S][D] bf16
    unsigned short* __restrict__ k_ws,   // [H][S][D] bf16
    unsigned short* __restrict__ v_ws)   // [H][D][S] bf16
{
    const int m0 = blockIdx.x * 64;
    const int n0 = blockIdx.y * 128;
    __shared__ union {
        struct { unsigned short Al[64 * 64]; unsigned short Bl[128 * 64]; } s;  // 24 KB
        unsigned short Cqk[64 * 136];   // 17.4 KB, stride 136 (272B, 16B-aligned rows)
        unsigned short Cv[128 * 72];    // 18.4 KB, stride 72 (144B, 16B-aligned rows)
    } sm;
    const int t = threadIdx.x;
    const int wave = t >> 6, lane = t & 63;
    const int quad = lane >> 4, l16 = lane & 15;

    const f32x4 zero = {0.f, 0.f, 0.f, 0.f};
    f32x4 acc[4][2];
    #pragma unroll
    for (int i = 0; i < 4; i++)
        #pragma unroll
        for (int j = 0; j < 2; j++) acc[i][j] = zero;

    for (int k0 = 0; k0 < KDIM; k0 += 64) {
        #pragma unroll
        for (int i = 0; i < 2; i++) {
            int c = (wave * 2 + i) * 64 + lane;
            int row = c >> 3;
            int kc = ((c & 7) ^ (row & 7)) * 8;
            gload_lds16(hidb + (size_t)(m0 + row) * KDIM + k0 + kc, sm.s.Al + (wave * 2 + i) * 512);
        }
        #pragma unroll
        for (int i = 0; i < 4; i++) {
            int c = (wave * 4 + i) * 64 + lane;
            int row = c >> 3;
            int kc = ((c & 7) ^ (row & 7)) * 8;
            gload_lds16(Wt + (size_t)(n0 + row) * KDIM + k0 + kc, sm.s.Bl + (wave * 4 + i) * 512);
        }
        __syncthreads();

        short8 af[2][4], bfr[2][2];
        #pragma unroll
        for (int rt = 0; rt < 4; rt++) {
            int rowA = rt * 16 + l16;
            #pragma unroll
            for (int s = 0; s < 2; s++)
                af[s][rt] = *(const short8*)(sm.s.Al + rowA * 64 + (((s << 2) | quad) ^ (rowA & 7)) * 8);
        }
        #pragma unroll
        for (int ct = 0; ct < 2; ct++) {
            int rowB = wave * 32 + ct * 16 + l16;
            #pragma unroll
            for (int s = 0; s < 2; s++)
                bfr[s][ct] = *(const short8*)(sm.s.Bl + rowB * 64 + (((s << 2) | quad) ^ (rowB & 7)) * 8);
        }
        #pragma unroll
        for (int s = 0; s < 2; s++)
            #pragma unroll
            for (int rt = 0; rt < 4; rt++)
                #pragma unroll
                for (int ct = 0; ct < 2; ct++)
                    acc[rt][ct] = __builtin_amdgcn_mfma_f32_16x16x32_bf16(af[s][rt], bfr[s][ct], acc[rt][ct], 0, 0, 0);
        __syncthreads();
    }

    const int mat = blockIdx.y / 6;
    const float* bm = (mat == 0) ? bq : (mat == 1 ? bk : bv);
    const float bscale = (mat == 0) ? 0.125f * LOG2E : 1.0f;

    if (mat != 2) {
        #pragma unroll
        for (int ct = 0; ct < 2; ct++) {
            int nloc = wave * 32 + ct * 16 + l16;
            float bias = bm[(n0 + nloc) - mat * 768] * bscale;
            #pragma unroll
            for (int rt = 0; rt < 4; rt++)
                #pragma unroll
                for (int r = 0; r < 4; r++)
                    sm.Cqk[(rt * 16 + quad * 4 + r) * 136 + nloc] = f2bf(acc[rt][ct][r] + bias);
        }
        __syncthreads();
        unsigned short* dst_ws = (mat == 0) ? q_ws : k_ws;
        #pragma unroll
        for (int p = 0; p < 4; p++) {
            int id = p * 256 + t;            // 1024 = 64 rows x 16 chunks
            int row = id >> 4, nc = id & 15;
            short8 val = *(const short8*)(sm.Cqk + row * 136 + nc * 8);
            int within = (n0 + nc * 8) - mat * 768;
            int head = within >> 6, dd = within & 63;
            *(short8*)(dst_ws + (size_t)head * (SEQ * HD) + (size_t)(m0 + row) * HD + dd) = val;
        }
    } else {
        #pragma unroll
        for (int ct = 0; ct < 2; ct++) {
            int nloc = wave * 32 + ct * 16 + l16;
            float bias = bm[(n0 + nloc) - 1536];
            #pragma unroll
            for (int rt = 0; rt < 4; rt++)
                #pragma unroll
                for (int r = 0; r < 4; r++)
                    sm.Cv[nloc * 72 + rt * 16 + quad * 4 + r] = f2bf(acc[rt][ct][r] + bias);
        }
        __syncthreads();
        #pragma unroll
        for (int p = 0; p < 4; p++) {
            int id = p * 256 + t;            // 1024 = 128 dd x 8 chunks
            int ddl = id >> 3;
            int sseg = (id & 7) * 8;
            short8 val = *(const short8*)(sm.Cv + ddl * 72 + sseg);
            int within = (n0 + ddl) - 1536;
            int head = within >> 6, dd = within & 63;
            *(short8*)(v_ws + (size_t)head * (HD * SEQ) + (size_t)dd * SEQ + m0 + sseg) = val;
        }
    }
}

// ---------------- Banded attention R5: LDS-shared K/V chunks (line-touch cut) ----------------
// Model fitting R0/R2/R4 (57.5/52.6/74.3 us): wall ~ 4 cyc x cache-lines
// touched per CU (27k/21k/39k lines -> 45/35/65 us predicted). The binding
// resource is the per-CU TA/L1 line pipe: every per-wave K/V fragment load
// touches ~16 scattered lines, re-touched by every wave. Fix: stage K and V^T
// 64-key chunks into LDS ONCE per 128-row WG (reg-staged so rows get a padded
// stride 72: 16B-aligned b128, worst 2-way bank alias = free per m136), shared
// by all 8 waves; keep R4's verified swapped-operand register-resident P math,
// fragments now from LDS. 384 WGs x 512 thr; 10 chunks double-buffered (39 KB
// LDS, 2 WGs/CU); T14 staging split (loads issued one chunk ahead, ds_write
// after compute). Line budget ~3300/WG -> ~26k cyc/CU ~ 11 us.
__global__ __launch_bounds__(512, 4) void attn_kernel(
    const unsigned short* __restrict__ q_ws,
    const unsigned short* __restrict__ k_ws,
    const unsigned short* __restrict__ v_ws,
    const float* __restrict__ amask,
    const unsigned char* __restrict__ imask,
    float* __restrict__ out)
{
    const int lbid = blockIdx.x;                  // 384 = 8 XCD * 48
    const int xcd = lbid & 7, slot = lbid >> 3;
    const int wg = xcd * 48 + slot;               // bijective (384 % 8 == 0)
    const int h = wg >> 5, cch = wg & 31;
    const int i0 = cch * 128;
    const int t = threadIdx.x;
    const int wave = t >> 6, lane = t & 63;
    const int quad = lane >> 4, l16 = lane & 15;
    const int rowoff = wave * 16 + l16;           // 0..127
    const int row_g = i0 + rowoff;

    __shared__ unsigned short Ksh[2][64 * 72];    // [key][dd], stride 72
    __shared__ unsigned short Vsh[2][64 * 72];    // [dd][key], stride 72
    __shared__ float fm[640];                     // per-key mask (log2 domain)

    const int jw = i0 - 256;                      // WG key-window origin
    for (int cc = t; cc < 640; cc += 512) {
        int j = jw + cc;
        fm[cc] = ((unsigned)j >= SEQ) ? -1e30f : ((amask[j] != 0.0f) ? LNEG * LOG2E : 0.0f);
    }

    // staging indices: one 16B K-granule + one 16B V-granule per thread per chunk
    const int srow = t >> 3;                      // 0..63 (key row for K, dd row for V)
    const int scol = (t & 7) * 8;                 // 0..56
    const unsigned short* kg = k_ws + h * (SEQ * HD) + scol;
    const unsigned short* vg = v_ws + h * (HD * SEQ) + (size_t)srow * SEQ;

    // stage chunk 0 directly
    {
        int jk = min(max(jw + srow, 0), SEQ - 1);
        int jv = min(max(jw + scol, 0), SEQ - 8);
        short8 kr = *(const short8*)(kg + (size_t)jk * HD);
        short8 vr = *(const short8*)(vg + jv);
        *(short8*)(&Ksh[0][srow * 72 + scol]) = kr;
        *(short8*)(&Vsh[0][srow * 72 + scol]) = vr;
    }
    // preload chunk 1 into registers (T14: issue early, write late)
    short8 kreg, vreg;
    {
        int jk = min(max(jw + 64 + srow, 0), SEQ - 1);
        int jv = min(max(jw + 64 + scol, 0), SEQ - 8);
        kreg = *(const short8*)(kg + (size_t)jk * HD);
        vreg = *(const short8*)(vg + jv);
    }

    // Q fragment (B-operand): col = qrow, k = dd
    const unsigned short* qb = q_ws + h * (SEQ * HD) + (size_t)row_g * HD + quad * 8;
    short8 a0 = *(const short8*)qb;
    short8 a1 = *(const short8*)(qb + 32);

    const f32x4 zero = {0.f, 0.f, 0.f, 0.f};
    f32x4 acc0 = zero, acc1 = zero, acc2 = zero, acc3 = zero;
    float sum = 0.f;

    for (int c = 0; c < 10; ++c) {
        __syncthreads();   // staged chunk c visible to all waves
        const unsigned short* Kb = Ksh[c & 1];
        const unsigned short* Vb = Vsh[c & 1];

        // ---- S^T: 4 key-tiles of 16; A = K[key][dd] from LDS, B = Q ----
        f32x4 st[4];
        #pragma unroll
        for (int tt = 0; tt < 4; ++tt) {
            const unsigned short* kp = Kb + (tt * 16 + l16) * 72 + quad * 8;
            short8 kf0 = *(const short8*)kp;
            short8 kf1 = *(const short8*)(kp + 32);
            f32x4 s = zero;
            s = __builtin_amdgcn_mfma_f32_16x16x32_bf16(kf0, a0, s, 0, 0, 0);
            s = __builtin_amdgcn_mfma_f32_16x16x32_bf16(kf1, a1, s, 0, 0, 0);
            st[tt] = s;
        }

        // ---- mask + exp2 + RNE-bf16 + row-sum (P stays in registers) ----
        unsigned short pb[16];
        #pragma unroll
        for (int tt = 0; tt < 4; ++tt) {
            f32x4 fmv = *(const f32x4*)(fm + 64 * c + 16 * tt + 4 * quad);
            #pragma unroll
            for (int r = 0; r < 4; ++r) {
                int cc = 64 * c + 16 * tt + 4 * quad + r;
                float arg = ((unsigned)(cc - rowoff) <= 512u) ? (st[tt][r] + fmv[r]) : -1e30f;
                unsigned short p = f2bf(__builtin_amdgcn_exp2f(arg));
                pb[tt * 4 + r] = p;
                sum += bf2f(p);
            }
        }

        // ---- PV: 2 key-groups of 32; A = V^T[dd][key] from LDS, B = packed P ----
        #pragma unroll
        for (int u = 0; u < 2; ++u) {
            union { unsigned int uu[4]; short8 s8; } pf;
            pf.uu[0] = (unsigned int)pb[8 * u + 0] | ((unsigned int)pb[8 * u + 1] << 16);
            pf.uu[1] = (unsigned int)pb[8 * u + 2] | ((unsigned int)pb[8 * u + 3] << 16);
            pf.uu[2] = (unsigned int)pb[8 * u + 4] | ((unsigned int)pb[8 * u + 5] << 16);
            pf.uu[3] = (unsigned int)pb[8 * u + 6] | ((unsigned int)pb[8 * u + 7] << 16);
            const unsigned short* vp0 = Vb + l16 * 72 + u * 32 + quad * 4;
            short4v v00 = *(const short4v*)(vp0);
            short4v v01 = *(const short4v*)(vp0 + 16);
            acc0 = __builtin_amdgcn_mfma_f32_16x16x32_bf16(cat8(v00, v01), pf.s8, acc0, 0, 0, 0);
            const unsigned short* vp1 = vp0 + 16 * 72;
            short4v v10 = *(const short4v*)(vp1);
            short4v v11 = *(const short4v*)(vp1 + 16);
            acc1 = __builtin_amdgcn_mfma_f32_16x16x32_bf16(cat8(v10, v11), pf.s8, acc1, 0, 0, 0);
            const unsigned short* vp2 = vp0 + 32 * 72;
            short4v v20 = *(const short4v*)(vp2);
            short4v v21 = *(const short4v*)(vp2 + 16);
            acc2 = __builtin_amdgcn_mfma_f32_16x16x32_bf16(cat8(v20, v21), pf.s8, acc2, 0, 0, 0);
            const unsigned short* vp3 = vp0 + 48 * 72;
            short4v v30 = *(const short4v*)(vp3);
            short4v v31 = *(const short4v*)(vp3 + 16);
            acc3 = __builtin_amdgcn_mfma_f32_16x16x32_bf16(cat8(v30, v31), pf.s8, acc3, 0, 0, 0);
        }

        // ---- stage chunk c+1 (other buffer; races impossible: barrier-separated) ----
        if (c < 9) {
            *(short8*)(&Ksh[(c + 1) & 1][srow * 72 + scol]) = kreg;
            *(short8*)(&Vsh[(c + 1) & 1][srow * 72 + scol]) = vreg;
            if (c < 8) {
                int jk = min(max(jw + 64 * (c + 2) + srow, 0), SEQ - 1);
                int jv = min(max(jw + 64 * (c + 2) + scol, 0), SEQ - 8);
                kreg = *(const short8*)(kg + (size_t)jk * HD);
                vreg = *(const short8*)(vg + jv);
            }
        }
    }

    // ---- row-sum across quads (lanes sharing l16), normalize, write O^T ----
    sum += __shfl_xor(sum, 16);
    sum += __shfl_xor(sum, 32);
    float rinv = imask[row_g] ? 0.f : __builtin_amdgcn_rcpf(sum);

    float* ob = out + (size_t)row_g * EMB + h * HD + quad * 4;
    f32x4 o;
    #pragma unroll
    for (int r = 0; r < 4; ++r) o[r] = acc0[r] * rinv;
    *(f32x4*)(ob) = o;
    #pragma unroll
    for (int r = 0; r < 4; ++r) o[r] = acc1[r] * rinv;
    *(f32x4*)(ob + 16) = o;
    #pragma unroll
    for (int r = 0; r < 4; ++r) o[r] = acc2[r] * rinv;
    *(f32x4*)(ob + 32) = o;
    #pragma unroll
    for (int r = 0; r < 4; ++r) o[r] = acc3[r] * rinv;
    *(f32x4*)(ob + 48) = o;
}

extern "C" void kernel_launch(void* const* d_in, const int* in_sizes, int n_in,
                              void* d_out, int out_size, void* d_ws, size_t ws_size,
                              hipStream_t stream) {
    (void)in_sizes; (void)n_in; (void)out_size; (void)ws_size;
    const float* hid = (const float*)d_in[0];
    const float* am  = (const float*)d_in[1];
    const unsigned char* im = (const unsigned char*)d_in[2];
    const float* Wq = (const float*)d_in[3];
    const float* bq = (const float*)d_in[4];
    const float* Wk = (const float*)d_in[5];
    const float* bk = (const float*)d_in[6];
    const float* Wv = (const float*)d_in[7];
    const float* bv = (const float*)d_in[8];
    float* out = (float*)d_out;

    unsigned short* ws = (unsigned short*)d_ws;
    unsigned short* q_ws = ws;
    unsigned short* k_ws = ws + (size_t)NH * SEQ * HD;
    unsigned short* v_ws = ws + 2 * (size_t)NH * SEQ * HD;
    unsigned short* hidb = (unsigned short*)d_out;   // d_out as scratch (attn overwrites last)
    unsigned short* Wt   = hidb + (size_t)SEQ * EMB;

    prep_kernel<<<dim3(1008), 256, 0, stream>>>(hid, Wq, Wk, Wv, hidb, Wt);
    gemm_kernel<<<dim3(64, 18), 256, 0, stream>>>(hidb, Wt, bq, bk, bv, q_ws, k_ws, v_ws);
    attn_kernel<<<dim3(384), 512, 0, stream>>>(q_ws, k_ws, v_ws, am, im, out);
}